// Round 2
// baseline (276.927 us; speedup 1.0000x reference)
//
#include <hip/hip_runtime.h>

// CSM_62216896250023: emb gather (16384,7,1024) -> 4 stacked depthwise seq-convs
// with sigmoid, seq 7->6->5->3->1, out (16384,1024) f32.
//
// R4b: R4 with the compile fix (__builtin_nontemporal_store needs a native
// ext_vector float4, not HIP_vector_type). Design rationale unchanged:
// R3 collapsed to VGPR_Count=44 (vs ~130 needed) -> compiler serialized
// gather/compute per row -> latency-bound at 40% HBM / 39% VALU. Fixes:
//  - weights prescaled into LDS (40KB/block), reloaded per row via
//    ds_read_b128 with a CSE-laundering opaque offset so they never occupy
//    40 VGPRs steady-state.
//  - all 56 row indices preloaded to SGPRs at block start (contiguous 224B).
//  - explicit double-buffered row gathers with sched_barrier(0) so next-row
//    loads stay in flight across current-row compute (reg demand ~108 < 128).
//  - nontemporal float4 output stores (write-once; keep L2 for emb reuse).

constexpr int EMBED = 1024;
constexpr int SEQ   = 7;
constexpr int ROWS  = 8;    // batch rows per block
constexpr int TAPS  = 10;   // c1(2) + c2(2) + c3(3) + c4(3)

typedef float f2 __attribute__((ext_vector_type(2)));
typedef float f4 __attribute__((ext_vector_type(4)));

__device__ __forceinline__ f2 sig2(f2 y) {
    // y = -log2(e) * preact (prescaled into weights);  sigmoid = 1/(1 + 2^y)
    f2 u;
    u.x = __builtin_amdgcn_exp2f(y.x);
    u.y = __builtin_amdgcn_exp2f(y.y);
    f2 d = u + (f2){1.0f, 1.0f};
    f2 r;
    r.x = __builtin_amdgcn_rcpf(d.x);
    r.y = __builtin_amdgcn_rcpf(d.y);
    return r;
}

__device__ __forceinline__ void gather_row(const float* __restrict__ emb,
                                           const int idx[SEQ],
                                           int e, f2 v[SEQ][2]) {
#pragma unroll
    for (int t = 0; t < SEQ; ++t) {
        const f4 f = *(const f4*)(emb + (size_t)idx[t] * EMBED + e);
        v[t][0] = (f2){f.x, f.y};
        v[t][1] = (f2){f.z, f.w};
    }
}

__device__ __forceinline__ void ldw(const float* wl, int tap, int e, f2 w[2]) {
    const f4 f = *(const f4*)(wl + tap * EMBED + e);   // ds_read_b128
    w[0] = (f2){f.x, f.y};
    w[1] = (f2){f.z, f.w};
}

__device__ __forceinline__ void compute_row(const f2 v[SEQ][2], const float* wl,
                                            int e, float* __restrict__ outp) {
    f2 wa[2], wb[2], wc[2];

    f2 h1[6][2];
    ldw(wl, 0, e, wa); ldw(wl, 1, e, wb);
#pragma unroll
    for (int l = 0; l < 6; ++l)
#pragma unroll
        for (int p = 0; p < 2; ++p)
            h1[l][p] = sig2(v[l][p] * wa[p] + v[l + 1][p] * wb[p]);

    f2 h2[5][2];
    ldw(wl, 2, e, wa); ldw(wl, 3, e, wb);
#pragma unroll
    for (int l = 0; l < 5; ++l)
#pragma unroll
        for (int p = 0; p < 2; ++p)
            h2[l][p] = sig2(h1[l][p] * wa[p] + h1[l + 1][p] * wb[p]);

    f2 h3[3][2];
    ldw(wl, 4, e, wa); ldw(wl, 5, e, wb); ldw(wl, 6, e, wc);
#pragma unroll
    for (int l = 0; l < 3; ++l)
#pragma unroll
        for (int p = 0; p < 2; ++p)
            h3[l][p] = sig2(h2[l][p] * wa[p] + h2[l + 1][p] * wb[p]
                            + h2[l + 2][p] * wc[p]);

    f2 o[2];
    ldw(wl, 7, e, wa); ldw(wl, 8, e, wb); ldw(wl, 9, e, wc);
#pragma unroll
    for (int p = 0; p < 2; ++p)
        o[p] = sig2(h3[0][p] * wa[p] + h3[1][p] * wb[p] + h3[2][p] * wc[p]);

    f4 of;
    of.x = o[0].x; of.y = o[0].y; of.z = o[1].x; of.w = o[1].y;
    __builtin_nontemporal_store(of, (f4*)outp);
}

__global__ __launch_bounds__(256, 4) void CSM_62216896250023_kernel(
    const int*   __restrict__ X,
    const float* __restrict__ emb,
    const float* __restrict__ c1,
    const float* __restrict__ c2,
    const float* __restrict__ c3,
    const float* __restrict__ c4,
    float*       __restrict__ out)
{
    __shared__ float wlds[TAPS * EMBED];

    const int tid = threadIdx.x;
    const int e   = tid << 2;
    const int b0  = blockIdx.x * ROWS;

    // ---- stage prescaled weights into LDS (once per block) ----
    const float NL2E = -1.44269504088896f;
    {
        const float* src[TAPS] = {c1, c1 + EMBED,
                                  c2, c2 + EMBED,
                                  c3, c3 + EMBED, c3 + 2 * EMBED,
                                  c4, c4 + EMBED, c4 + 2 * EMBED};
#pragma unroll
        for (int t = 0; t < TAPS; ++t) {          // t compile-time: src[t] folds
            f4 f = *(const f4*)(src[t] + e);
            f *= NL2E;
            *(f4*)&wlds[t * EMBED + e] = f;
        }
    }

    // ---- preload all 56 indices (uniform -> SGPRs, contiguous 224B of X) ----
    int idx[ROWS][SEQ];
#pragma unroll
    for (int r = 0; r < ROWS; ++r)
#pragma unroll
        for (int t = 0; t < SEQ; ++t)
            idx[r][t] = X[(b0 + r) * SEQ + t];

    __syncthreads();

    // ---- double-buffered row pipeline ----
    f2 v[2][SEQ][2];
    gather_row(emb, idx[0], e, v[0]);
#pragma unroll
    for (int r = 0; r < ROWS; ++r) {
        if (r + 1 < ROWS) gather_row(emb, idx[r + 1], e, v[(r + 1) & 1]);
        // Fence: next-row gathers must stay issued above this point; compute
        // below waits only on the PREVIOUS row's loads (counted vmcnt).
        __builtin_amdgcn_sched_barrier(0);
        // Opaque zero per row: defeats CSE/LICM re-hoisting the 10 LDS tap
        // reads into 40 permanently-live VGPRs across the unrolled rows.
        unsigned rofs = 0;
        asm volatile("" : "+v"(rofs));
        compute_row(v[r & 1], (const float*)wlds + rofs, e,
                    out + (size_t)(b0 + r) * EMBED + e);
    }
}

extern "C" void kernel_launch(void* const* d_in, const int* in_sizes, int n_in,
                              void* d_out, int out_size, void* d_ws, size_t ws_size,
                              hipStream_t stream) {
    const int*   X   = (const int*)d_in[0];
    const float* emb = (const float*)d_in[1];
    const float* c1  = (const float*)d_in[2];
    const float* c2  = (const float*)d_in[3];
    const float* c3  = (const float*)d_in[4];
    const float* c4  = (const float*)d_in[5];
    float* out = (float*)d_out;

    const int batch = in_sizes[0] / SEQ;        // 16384
    CSM_62216896250023_kernel<<<batch / ROWS, 256, 0, stream>>>(X, emb, c1, c2, c3, c4, out);
}

// Round 3
// 247.824 us; speedup vs baseline: 1.1174x; 1.1174x over previous
//
#include <hip/hip_runtime.h>

// CSM_62216896250023: emb gather (16384,7,1024) -> 4 stacked depthwise seq-convs
// with sigmoid, seq 7->6->5->3->1, out (16384,1024) f32.
//
// R5: hand-rolled gather pipeline in inline asm. History: R3 (reg pipeline,
// bounds(256,4)) collapsed to VGPR=44 -> serialized, 93us. R4b (LDS weights +
// sched_barrier) spilled under the same cap (VGPR=64, WRITE 64->140MB), 125us.
// Counters pin VALU demand at ~36us and memory at ~46us -> overlapped target
// ~55us. The compiler will not hold a 7-load-deep pipeline across a row of
// compute at HIP level, so the pipeline is now explicit:
//  - gathers: asm global_load_dwordx4 (saddr = uniform row pointer via
//    readfirstlane, voffset = tid*16). Results in named f4 regs.
//  - counted waits: asm s_waitcnt vmcnt(N), N exact per iteration
//    (r=0: 7 = next row's loads; r=1..6: 8 = 1 store + 7 loads; r=7: 1).
//    sched_barrier(0) after each wait (rule: compiler hoists reg-only VALU
//    past inline-asm waitcnt otherwise).
//  - stores: asm global_store_dwordx4 so the vmcnt count stays deterministic.
//  - weights prescaled (-log2e) in LDS: weight reads are lgkmcnt, NOT vmcnt,
//    so compiler-managed weight traffic cannot pollute the counted waits.
//  - idx loads are uniform -> SMEM (lgkmcnt) -> no vmcnt pollution either.
//  - no launch_bounds occupancy floor: no forced spill. LDS 40KB caps
//    occupancy at 4 blocks/CU = 16 waves/CU, enough to saturate VALU issue
//    when each wave self-hides latency.

constexpr int EMBED = 1024;
constexpr int SEQ   = 7;
constexpr int ROWS  = 8;    // batch rows per block
constexpr int TAPS  = 10;   // c1(2) + c2(2) + c3(3) + c4(3)

typedef float f2 __attribute__((ext_vector_type(2)));
typedef float f4 __attribute__((ext_vector_type(4)));

__device__ __forceinline__ f2 sig2(f2 y) {
    // y = -log2(e) * preact (scale folded into weights);  sigmoid = 1/(1 + 2^y)
    f2 u;
    u.x = __builtin_amdgcn_exp2f(y.x);
    u.y = __builtin_amdgcn_exp2f(y.y);
    f2 d = u + (f2){1.0f, 1.0f};
    f2 r;
    r.x = __builtin_amdgcn_rcpf(d.x);
    r.y = __builtin_amdgcn_rcpf(d.y);
    return r;
}

__device__ __forceinline__ f2 vhalf(f4 f, int p) {
    return p ? (f2){f.z, f.w} : (f2){f.x, f.y};
}

// Issue 7 gather loads for one row; results land in v[0..6] with NO wait.
__device__ __forceinline__ void issue_row_loads(const float* __restrict__ emb,
                                                const int idx7[SEQ],
                                                unsigned voff, f4 v[SEQ]) {
#pragma unroll
    for (int t = 0; t < SEQ; ++t) {
        const float* p = emb + ((size_t)(unsigned)idx7[t]) * EMBED;  // scalar
        asm volatile("global_load_dwordx4 %0, %1, %2"
                     : "=v"(v[t])
                     : "v"(voff), "s"(p));
    }
}

__device__ __forceinline__ void store_row(float* obase, unsigned voff, f4 val) {
    asm volatile("global_store_dwordx4 %0, %1, %2"
                 :: "v"(voff), "v"(val), "s"(obase)
                 : "memory");
}

__device__ __forceinline__ f2 ldw2(const float* wl, int tap, int e, int p) {
    return *(const f2*)(wl + tap * EMBED + e + 2 * p);    // ds_read_b64
}

// p-outer compute: halves live temps vs computing both f2 lanes jointly.
__device__ __forceinline__ f4 compute_row(const f4 v[SEQ], const float* wl, int e) {
    f2 o[2];
#pragma unroll
    for (int p = 0; p < 2; ++p) {
        f2 wa = ldw2(wl, 0, e, p), wb = ldw2(wl, 1, e, p), wc;
        f2 h1[6];
#pragma unroll
        for (int l = 0; l < 6; ++l)
            h1[l] = sig2(vhalf(v[l], p) * wa + vhalf(v[l + 1], p) * wb);
        wa = ldw2(wl, 2, e, p); wb = ldw2(wl, 3, e, p);
        f2 h2[5];
#pragma unroll
        for (int l = 0; l < 5; ++l)
            h2[l] = sig2(h1[l] * wa + h1[l + 1] * wb);
        wa = ldw2(wl, 4, e, p); wb = ldw2(wl, 5, e, p); wc = ldw2(wl, 6, e, p);
        f2 h3[3];
#pragma unroll
        for (int l = 0; l < 3; ++l)
            h3[l] = sig2(h2[l] * wa + h2[l + 1] * wb + h2[l + 2] * wc);
        wa = ldw2(wl, 7, e, p); wb = ldw2(wl, 8, e, p); wc = ldw2(wl, 9, e, p);
        o[p] = sig2(h3[0] * wa + h3[1] * wb + h3[2] * wc);
    }
    f4 of;
    of.x = o[0].x; of.y = o[0].y; of.z = o[1].x; of.w = o[1].y;
    return of;
}

__global__ __launch_bounds__(256) void CSM_62216896250023_kernel(
    const int*   __restrict__ X,
    const float* __restrict__ emb,
    const float* __restrict__ c1,
    const float* __restrict__ c2,
    const float* __restrict__ c3,
    const float* __restrict__ c4,
    float*       __restrict__ out)
{
    __shared__ float wlds[TAPS * EMBED];

    const int tid = threadIdx.x;
    const int e   = tid << 2;               // float index, 4 per thread
    const unsigned voff = (unsigned)e * 4u; // byte offset for asm loads/stores
    const int b0  = blockIdx.x * ROWS;

    // ---- stage prescaled weights into LDS (once per block) ----
    const float NL2E = -1.44269504088896f;
    {
        const float* src[TAPS] = {c1, c1 + EMBED,
                                  c2, c2 + EMBED,
                                  c3, c3 + EMBED, c3 + 2 * EMBED,
                                  c4, c4 + EMBED, c4 + 2 * EMBED};
#pragma unroll
        for (int t = 0; t < TAPS; ++t) {          // t compile-time: src[t] folds
            f4 f = *(const f4*)(src[t] + e);
            f *= NL2E;
            *(f4*)&wlds[t * EMBED + e] = f;
        }
    }

    // ---- indices: uniform address -> SMEM loads (lgkmcnt, not vmcnt) ----
    int idx[ROWS][SEQ];
#pragma unroll
    for (int r = 0; r < ROWS; ++r)
#pragma unroll
        for (int t = 0; t < SEQ; ++t)
            idx[r][t] = __builtin_amdgcn_readfirstlane(X[(b0 + r) * SEQ + t]);

    __syncthreads();

    // ---- explicit double-buffered gather pipeline ----
    f4 va[SEQ], vb[SEQ];
    issue_row_loads(emb, idx[0], voff, va);

#pragma unroll
    for (int r = 0; r < ROWS; ++r) {
        // 1) issue next row's 7 loads (into the buffer not being consumed)
        if (r + 1 < ROWS) {
            if (r & 1) issue_row_loads(emb, idx[r + 1], voff, va);
            else       issue_row_loads(emb, idx[r + 1], voff, vb);
        }
        // 2) counted wait: exactly drain row r's loads, keep row r+1 in flight.
        //    Outstanding younger than row r's loads: r=0 -> 7 (next loads);
        //    r=1..6 -> 8 (store r-1 + next loads); r=7 -> 1 (store r-1).
        if (r == 0)              asm volatile("s_waitcnt vmcnt(7)" ::: "memory");
        else if (r == ROWS - 1)  asm volatile("s_waitcnt vmcnt(1)" ::: "memory");
        else                     asm volatile("s_waitcnt vmcnt(8)" ::: "memory");
        __builtin_amdgcn_sched_barrier(0);

        // 3) compute + store (store via asm keeps vmcnt arithmetic exact).
        //    Opaque zero defeats LICM re-hoisting the per-row LDS weight
        //    reads into 40 permanently-live VGPRs.
        unsigned rofs = 0;
        asm volatile("" : "+v"(rofs));
        const float* wl = (const float*)wlds + rofs;
        f4 o = (r & 1) ? compute_row(vb, wl, e) : compute_row(va, wl, e);
        store_row(out + (size_t)(b0 + r) * EMBED, voff, o);
    }

    // stores are invisible to the compiler -> explicit drain before endpgm
    asm volatile("s_waitcnt vmcnt(0)" ::: "memory");
}

extern "C" void kernel_launch(void* const* d_in, const int* in_sizes, int n_in,
                              void* d_out, int out_size, void* d_ws, size_t ws_size,
                              hipStream_t stream) {
    const int*   X   = (const int*)d_in[0];
    const float* emb = (const float*)d_in[1];
    const float* c1  = (const float*)d_in[2];
    const float* c2  = (const float*)d_in[3];
    const float* c3  = (const float*)d_in[4];
    const float* c4  = (const float*)d_in[5];
    float* out = (float*)d_out;

    const int batch = in_sizes[0] / SEQ;        // 16384
    CSM_62216896250023_kernel<<<batch / ROWS, 256, 0, stream>>>(X, emb, c1, c2, c3, c4, out);
}